// Round 2
// baseline (1131.002 us; speedup 1.0000x reference)
//
#include <hip/hip_runtime.h>
#include <hip/hip_bf16.h>

typedef unsigned short us;
typedef unsigned int   u32;
typedef __bf16 bf16_t;
typedef bf16_t bf16x8 __attribute__((ext_vector_type(8)));
typedef float  f32x4  __attribute__((ext_vector_type(4)));
typedef us     usx4   __attribute__((ext_vector_type(4)));
typedef us     usx8   __attribute__((ext_vector_type(8)));

#define HWSZ 65536   // 256*256

__device__ __forceinline__ float b2f(us u) {
    union { u32 i; float f; } t; t.i = ((u32)u) << 16; return t.f;
}
__device__ __forceinline__ us f2b(float f) {
    union { float f; u32 i; } t; t.f = f;
    u32 r = t.i + 0x7fff + ((t.i >> 16) & 1);   // RNE
    return (us)(r >> 16);
}
// async global->LDS, 16B per lane. LDS dest is wave-uniform base + lane*16.
__device__ __forceinline__ void gl_lds16(const us* g, us* l) {
    __builtin_amdgcn_global_load_lds(
        (const __attribute__((address_space(1))) u32*)g,
        (__attribute__((address_space(3))) u32*)l, 16, 0, 0);
}

// ---------------------------------------------------------------------------
// prep: weights -> bf16 (already [o][c] = N-major K-contiguous), BN fold.
__global__ __launch_bounds__(256) void prep(
        const float* __restrict__ qkv_w, const float* __restrict__ pw_w,
        const float* __restrict__ g, const float* __restrict__ bt,
        const float* __restrict__ mn, const float* __restrict__ vr,
        us* __restrict__ wb, us* __restrict__ pwb, float* __restrict__ ivad) {
    int tid = blockIdx.x * 256 + threadIdx.x;
    if (tid < 768 * 256) wb[tid] = f2b(qkv_w[tid]);
    if (tid < 256 * 256) pwb[tid] = f2b(pw_w[tid]);
    if (tid < 256) {
        float iv = g[tid] / sqrtf(vr[tid] + 1e-5f);
        ivad[tid] = iv;
        ivad[256 + tid] = bt[tid] - mn[tid] * iv;
    }
}

// ---------------------------------------------------------------------------
// transpose_x: x NCHW f32 -> xt NHWC bf16  (tile 64c x 64p via LDS)
__global__ __launch_bounds__(256) void transpose_x(
        const float* __restrict__ x, us* __restrict__ xt) {
    __shared__ float ls[64][65];
    const int b  = blockIdx.z;
    const int c0 = blockIdx.y * 64;
    const int p0 = blockIdx.x * 64;
    const int tid = threadIdx.x;
    const int tr  = tid >> 4;          // 0..15
    const int tc4 = (tid & 15) << 2;   // 0..60
    const float* xb = x + ((size_t)b * 256 + c0) * HWSZ + p0;
    #pragma unroll
    for (int q = 0; q < 4; ++q) {
        int c = tr + 16 * q;
        float4 v = *(const float4*)&xb[(size_t)c * HWSZ + tc4];
        ls[c][tc4 + 0] = v.x; ls[c][tc4 + 1] = v.y;
        ls[c][tc4 + 2] = v.z; ls[c][tc4 + 3] = v.w;
    }
    __syncthreads();
    #pragma unroll
    for (int q = 0; q < 4; ++q) {
        int pp = tr + 16 * q;
        usx4 o;
        o[0] = f2b(ls[tc4 + 0][pp]); o[1] = f2b(ls[tc4 + 1][pp]);
        o[2] = f2b(ls[tc4 + 2][pp]); o[3] = f2b(ls[tc4 + 3][pp]);
        *(usx4*)&xt[((size_t)b * HWSZ + p0 + pp) * 256 + c0 + tc4] = o;
    }
}

// ---------------------------------------------------------------------------
// qkv_mfma: C[p,o] = xt[p,:] . wb[o,:]   M=65536 N=768 K=256 per batch, bf16
// m97 structure: 128x128 tile, BK=32, 4 waves (2x2), 4x4 16x16x32 frags/wave.
__global__ __launch_bounds__(256) void qkv_mfma(
        const us* __restrict__ xt, const us* __restrict__ wb,
        us* __restrict__ qkv) {
    __shared__ __align__(16) us As[128 * 32];
    __shared__ __align__(16) us Bs[128 * 32];
    const int tid  = threadIdx.x;
    const int wv   = tid >> 6;
    const int lane = tid & 63;
    const int p0 = blockIdx.x * 128;
    const int o0 = blockIdx.y * 128;
    const int b  = blockIdx.z;
    const us* Ab = xt + ((size_t)b * HWSZ + p0) * 256;
    const us* Bb = wb + (size_t)o0 * 256;
    const int lr = lane & 15;
    const int k8 = lane >> 4;
    const int wm = wv >> 1, wn = wv & 1;
    const int srow = lane >> 2;          // staging row within 16-row chunk
    const int sch  = (lane & 3) << 3;    // staging element offset (8 bf16=16B)

    f32x4 acc[4][4];
    #pragma unroll
    for (int i = 0; i < 4; ++i)
        #pragma unroll
        for (int j = 0; j < 4; ++j) acc[i][j] = (f32x4){0.f, 0.f, 0.f, 0.f};

    for (int kt = 0; kt < 8; ++kt) {
        const int c0 = kt * 32;
        #pragma unroll
        for (int i = 0; i < 2; ++i) {
            int rb = 32 * wv + 16 * i;
            gl_lds16(Ab + (size_t)(rb + srow) * 256 + c0 + sch, &As[rb * 32]);
            gl_lds16(Bb + (size_t)(rb + srow) * 256 + c0 + sch, &Bs[rb * 32]);
        }
        __syncthreads();   // drains vmcnt before any wave reads LDS
        bf16x8 af[4], bg[4];
        #pragma unroll
        for (int i = 0; i < 4; ++i)
            af[i] = *(const bf16x8*)&As[(64 * wm + 16 * i + lr) * 32 + k8 * 8];
        #pragma unroll
        for (int j = 0; j < 4; ++j)
            bg[j] = *(const bf16x8*)&Bs[(64 * wn + 16 * j + lr) * 32 + k8 * 8];
        #pragma unroll
        for (int i = 0; i < 4; ++i)
            #pragma unroll
            for (int j = 0; j < 4; ++j)
                acc[i][j] = __builtin_amdgcn_mfma_f32_16x16x32_bf16(
                    af[i], bg[j], acc[i][j], 0, 0, 0);
        __syncthreads();
    }
    // C/D layout: col = lane&15, row = (lane>>4)*4 + reg   (row=p, col=o)
    #pragma unroll
    for (int i = 0; i < 4; ++i) {
        int pr = p0 + 64 * wm + 16 * i + 4 * k8;
        #pragma unroll
        for (int j = 0; j < 4; ++j) {
            int oc = o0 + 64 * wn + 16 * j + lr;
            #pragma unroll
            for (int rr = 0; rr < 4; ++rr)
                qkv[((size_t)b * HWSZ + pr + rr) * 768 + oc] = f2b(acc[i][j][rr]);
        }
    }
}

// ---------------------------------------------------------------------------
// attn: one wave per (batch, window, head); NHWC qkv; residual from xt (bf16).
__global__ __launch_bounds__(64) void attn_kernel(
        const us* __restrict__ qkv, const us* __restrict__ xt,
        const float* __restrict__ bias_table, us* __restrict__ att) {
    const int bx = blockIdx.x;
    const int head = bx & 15;
    const int w = (bx >> 4) & 1023;
    const int b = bx >> 14;
    const int wy = w >> 5, wx = w & 31;
    const int t = threadIdx.x;
    const int p = (wy * 8 + (t >> 3)) * 256 + wx * 8 + (t & 7);
    const size_t rowb = (size_t)b * HWSZ + p;
    const size_t gq = rowb * 768 + head * 16;

    __shared__ float ks[64][20];   // 80B rows: float4-aligned, conflict-light
    __shared__ float vs[64][20];
    __shared__ float bias_s[228];

    usx8 k0v = *(const usx8*)&qkv[gq + 256];
    usx8 k1v = *(const usx8*)&qkv[gq + 256 + 8];
    usx8 v0v = *(const usx8*)&qkv[gq + 512];
    usx8 v1v = *(const usx8*)&qkv[gq + 512 + 8];
    #pragma unroll
    for (int d = 0; d < 8; ++d) {
        ks[t][d] = b2f(k0v[d]); ks[t][d + 8] = b2f(k1v[d]);
        vs[t][d] = b2f(v0v[d]); vs[t][d + 8] = b2f(v1v[d]);
    }
    usx8 q0 = *(const usx8*)&qkv[gq];
    usx8 q1 = *(const usx8*)&qkv[gq + 8];
    float qr[16];
    #pragma unroll
    for (int d = 0; d < 8; ++d) {
        qr[d] = b2f(q0[d]) * 0.25f; qr[d + 8] = b2f(q1[d]) * 0.25f;
    }
    #pragma unroll
    for (int r = 0; r < 4; ++r) {
        int idx = r * 64 + t;
        if (idx < 225) bias_s[idx] = bias_table[idx * 16 + head];
    }
    __syncthreads();

    float dots[64];
    #pragma unroll 16
    for (int j = 0; j < 64; ++j) {
        float kk[16];
        *(float4*)&kk[0]  = *(const float4*)&ks[j][0];   // broadcast reads
        *(float4*)&kk[4]  = *(const float4*)&ks[j][4];
        *(float4*)&kk[8]  = *(const float4*)&ks[j][8];
        *(float4*)&kk[12] = *(const float4*)&ks[j][12];
        float s = 0.f;
        #pragma unroll
        for (int d = 0; d < 16; ++d) s = fmaf(qr[d], kk[d], s);
        dots[j] = s;
    }
    const int iy = t >> 3, ix = t & 7;
    float mx = -1e30f;
    #pragma unroll
    for (int j = 0; j < 64; ++j) {
        int jy = j >> 3, jx = j & 7;
        dots[j] += bias_s[(iy - jy + 7) * 15 + (ix - jx + 7)];
        mx = fmaxf(mx, dots[j]);
    }
    float ssum = 0.f;
    #pragma unroll
    for (int j = 0; j < 64; ++j) {
        float e = __expf(dots[j] - mx);
        dots[j] = e; ssum += e;
    }
    const float sinv = 1.0f / ssum;

    float o[16];
    #pragma unroll
    for (int d = 0; d < 16; ++d) o[d] = 0.f;
    #pragma unroll 16
    for (int j = 0; j < 64; ++j) {
        float vv[16];
        *(float4*)&vv[0]  = *(const float4*)&vs[j][0];
        *(float4*)&vv[4]  = *(const float4*)&vs[j][4];
        *(float4*)&vv[8]  = *(const float4*)&vs[j][8];
        *(float4*)&vv[12] = *(const float4*)&vs[j][12];
        float a = dots[j];
        #pragma unroll
        for (int d = 0; d < 16; ++d) o[d] = fmaf(a, vv[d], o[d]);
    }
    usx8 r0 = *(const usx8*)&xt[rowb * 256 + head * 16];
    usx8 r1 = *(const usx8*)&xt[rowb * 256 + head * 16 + 8];
    usx8 s0, s1;
    #pragma unroll
    for (int d = 0; d < 8; ++d) {
        s0[d] = f2b(o[d] * sinv + b2f(r0[d]));
        s1[d] = f2b(o[d + 8] * sinv + b2f(r1[d]));
    }
    *(usx8*)&att[rowb * 256 + head * 16]     = s0;
    *(usx8*)&att[rowb * 256 + head * 16 + 8] = s1;
}

// ---------------------------------------------------------------------------
// dwbn: NHWC depthwise 3x3 (zero-pad conv over reflect(+1) padded field) + BN
// thread: 4 channels (weights in regs), 64 pixels via chunk loop.
__global__ __launch_bounds__(256) void dwbn(
        const us* __restrict__ att, const float* __restrict__ dw_w,
        const float* __restrict__ ivad, us* __restrict__ ybn) {
    const int tid = threadIdx.x;
    const int cg = tid & 63;          // channel group (4 ch)
    const int pl = tid >> 6;          // 0..3
    const int b  = blockIdx.y;
    const int pbase = blockIdx.x * 256;
    const int c4 = cg * 4;
    float w[9][4], iv[4], ad[4];
    #pragma unroll
    for (int cc = 0; cc < 4; ++cc) {
        #pragma unroll
        for (int k = 0; k < 9; ++k) w[k][cc] = dw_w[(c4 + cc) * 9 + k];
        iv[cc] = ivad[c4 + cc];
        ad[cc] = ivad[256 + c4 + cc];
    }
    const us* ab = att + (size_t)b * HWSZ * 256;
    us* yb = ybn + (size_t)b * HWSZ * 256;
    for (int ch = 0; ch < 64; ++ch) {
        const int p = pbase + ch * 4 + pl;
        const int y = p >> 8, x = p & 255;
        float acc[4] = {0.f, 0.f, 0.f, 0.f};
        #pragma unroll
        for (int dy = -1; dy <= 1; ++dy) {
            int yy = y + dy;
            if (yy < 0) continue;        // zero pad (conv)
            if (yy > 255) yy = 254;      // reflect pad (pad_out)
            #pragma unroll
            for (int dx = -1; dx <= 1; ++dx) {
                int xx = x + dx;
                if (xx < 0) continue;
                if (xx > 255) xx = 254;
                usx4 vv = *(const usx4*)&ab[((size_t)(yy << 8) + xx) * 256 + c4];
                const int k = (dy + 1) * 3 + dx + 1;
                acc[0] = fmaf(w[k][0], b2f(vv[0]), acc[0]);
                acc[1] = fmaf(w[k][1], b2f(vv[1]), acc[1]);
                acc[2] = fmaf(w[k][2], b2f(vv[2]), acc[2]);
                acc[3] = fmaf(w[k][3], b2f(vv[3]), acc[3]);
            }
        }
        usx4 o;
        o[0] = f2b(acc[0] * iv[0] + ad[0]);
        o[1] = f2b(acc[1] * iv[1] + ad[1]);
        o[2] = f2b(acc[2] * iv[2] + ad[2]);
        o[3] = f2b(acc[3] * iv[3] + ad[3]);
        *(usx4*)&yb[(size_t)p * 256 + c4] = o;
    }
}

// ---------------------------------------------------------------------------
// pw_mfma: out[o,p] (NCHW f32) = ybn[p,:] . pwb[o,:]   M=65536 N=256 K=256
__global__ __launch_bounds__(256) void pw_mfma(
        const us* __restrict__ ybn, const us* __restrict__ pwb,
        float* __restrict__ out) {
    __shared__ __align__(16) us As[128 * 32];
    __shared__ __align__(16) us Bs[128 * 32];
    const int tid  = threadIdx.x;
    const int wv   = tid >> 6;
    const int lane = tid & 63;
    const int p0 = blockIdx.x * 128;
    const int o0 = blockIdx.y * 128;
    const int b  = blockIdx.z;
    const us* Ab = ybn + ((size_t)b * HWSZ + p0) * 256;
    const us* Bb = pwb + (size_t)o0 * 256;
    const int lr = lane & 15;
    const int k8 = lane >> 4;
    const int wm = wv >> 1, wn = wv & 1;
    const int srow = lane >> 2;
    const int sch  = (lane & 3) << 3;

    f32x4 acc[4][4];
    #pragma unroll
    for (int i = 0; i < 4; ++i)
        #pragma unroll
        for (int j = 0; j < 4; ++j) acc[i][j] = (f32x4){0.f, 0.f, 0.f, 0.f};

    for (int kt = 0; kt < 8; ++kt) {
        const int c0 = kt * 32;
        #pragma unroll
        for (int i = 0; i < 2; ++i) {
            int rb = 32 * wv + 16 * i;
            gl_lds16(Ab + (size_t)(rb + srow) * 256 + c0 + sch, &As[rb * 32]);
            gl_lds16(Bb + (size_t)(rb + srow) * 256 + c0 + sch, &Bs[rb * 32]);
        }
        __syncthreads();
        bf16x8 af[4], bg[4];
        #pragma unroll
        for (int i = 0; i < 4; ++i)
            af[i] = *(const bf16x8*)&As[(64 * wm + 16 * i + lr) * 32 + k8 * 8];
        #pragma unroll
        for (int j = 0; j < 4; ++j)
            bg[j] = *(const bf16x8*)&Bs[(64 * wn + 16 * j + lr) * 32 + k8 * 8];
        #pragma unroll
        for (int i = 0; i < 4; ++i)
            #pragma unroll
            for (int j = 0; j < 4; ++j)
                acc[i][j] = __builtin_amdgcn_mfma_f32_16x16x32_bf16(
                    af[i], bg[j], acc[i][j], 0, 0, 0);
        __syncthreads();
    }
    // row=p (4 consecutive per lane) -> float4 store into NCHW out[o][p]
    #pragma unroll
    for (int i = 0; i < 4; ++i) {
        int pr = p0 + 64 * wm + 16 * i + 4 * k8;
        #pragma unroll
        for (int j = 0; j < 4; ++j) {
            int oc = o0 + 64 * wn + 16 * j + lr;
            *(f32x4*)&out[((size_t)b * 256 + oc) * HWSZ + pr] = acc[i][j];
        }
    }
}

// ---------------------------------------------------------------------------
extern "C" void kernel_launch(void* const* d_in, const int* in_sizes, int n_in,
                              void* d_out, int out_size, void* d_ws, size_t ws_size,
                              hipStream_t stream) {
    const float* x          = (const float*)d_in[0];
    const float* qkv_w      = (const float*)d_in[1];
    const float* bias_table = (const float*)d_in[2];
    const float* dw_w       = (const float*)d_in[3];
    const float* bn_gamma   = (const float*)d_in[4];
    const float* bn_beta    = (const float*)d_in[5];
    const float* bn_mean    = (const float*)d_in[6];
    const float* bn_var     = (const float*)d_in[7];
    const float* pw_w       = (const float*)d_in[8];
    float* out = (float*)d_out;

    // workspace layout (ybn aliases xt: xt is dead after attn)
    char* ws = (char*)d_ws;
    us*    xt   = (us*)ws;                          //  67,108,864 B
    us*    qkv  = (us*)(ws + 67108864);             // 201,326,592 B
    us*    att  = (us*)(ws + 268435456);            //  67,108,864 B
    us*    wb   = (us*)(ws + 335544320);            //     393,216 B
    us*    pwb  = (us*)(ws + 335937536);            //     131,072 B
    float* ivad = (float*)(ws + 336068608);         //       2,048 B
    us*    ybn  = xt;                               // alias

    prep<<<768, 256, 0, stream>>>(qkv_w, pw_w, bn_gamma, bn_beta, bn_mean,
                                  bn_var, wb, pwb, ivad);
    transpose_x<<<dim3(1024, 4, 2), 256, 0, stream>>>(x, xt);
    qkv_mfma<<<dim3(512, 6, 2), 256, 0, stream>>>(xt, wb, qkv);
    attn_kernel<<<2 * 1024 * 16, 64, 0, stream>>>(qkv, xt, bias_table, att);
    dwbn<<<dim3(256, 2), 256, 0, stream>>>(att, dw_w, ivad, ybn);
    pw_mfma<<<dim3(512, 2, 2), 256, 0, stream>>>(ybn, pwb, out);
}

// Round 3
// 985.448 us; speedup vs baseline: 1.1477x; 1.1477x over previous
//
#include <hip/hip_runtime.h>
#include <hip/hip_bf16.h>

typedef unsigned short us;
typedef unsigned int   u32;
typedef __bf16 bf16_t;
typedef bf16_t bf16x8 __attribute__((ext_vector_type(8)));
typedef float  f32x4  __attribute__((ext_vector_type(4)));
typedef us     usx4   __attribute__((ext_vector_type(4)));
typedef us     usx8   __attribute__((ext_vector_type(8)));

#define HWSZ 65536   // 256*256

__device__ __forceinline__ float b2f(us u) {
    union { u32 i; float f; } t; t.i = ((u32)u) << 16; return t.f;
}
__device__ __forceinline__ us f2b(float f) {
    union { float f; u32 i; } t; t.f = f;
    u32 r = t.i + 0x7fff + ((t.i >> 16) & 1);   // RNE
    return (us)(r >> 16);
}
// async global->LDS, 16B/lane. LDS dest = wave-uniform base + lane*16B;
// global src is per-lane.
__device__ __forceinline__ void gl_lds16(const us* g, us* l) {
    __builtin_amdgcn_global_load_lds(
        (const __attribute__((address_space(1))) u32*)g,
        (__attribute__((address_space(3))) u32*)l, 16, 0, 0);
}

// ---------------------------------------------------------------------------
// prep: weights -> bf16; q-block (o<256) pre-scaled by d^-0.5 = 0.25; BN fold.
__global__ __launch_bounds__(256) void prep(
        const float* __restrict__ qkv_w, const float* __restrict__ pw_w,
        const float* __restrict__ g, const float* __restrict__ bt,
        const float* __restrict__ mn, const float* __restrict__ vr,
        us* __restrict__ wb, us* __restrict__ pwb, float* __restrict__ ivad) {
    int tid = blockIdx.x * 256 + threadIdx.x;
    if (tid < 768 * 256) {
        int o = tid >> 8;
        float v = qkv_w[tid];
        if (o < 256) v *= 0.25f;
        wb[tid] = f2b(v);
    }
    if (tid < 256 * 256) pwb[tid] = f2b(pw_w[tid]);
    if (tid < 256) {
        float iv = g[tid] / sqrtf(vr[tid] + 1e-5f);
        ivad[tid] = iv;
        ivad[256 + tid] = bt[tid] - mn[tid] * iv;
    }
}

// ---------------------------------------------------------------------------
// transpose_x: x NCHW f32 -> xt NHWC bf16  (tile 64c x 64p via LDS)
__global__ __launch_bounds__(256) void transpose_x(
        const float* __restrict__ x, us* __restrict__ xt) {
    __shared__ float ls[64][65];
    const int b  = blockIdx.z;
    const int c0 = blockIdx.y * 64;
    const int p0 = blockIdx.x * 64;
    const int tid = threadIdx.x;
    const int tr  = tid >> 4;          // 0..15
    const int tc4 = (tid & 15) << 2;   // 0..60
    const float* xb = x + ((size_t)b * 256 + c0) * HWSZ + p0;
    #pragma unroll
    for (int q = 0; q < 4; ++q) {
        int c = tr + 16 * q;
        float4 v = *(const float4*)&xb[(size_t)c * HWSZ + tc4];
        ls[c][tc4 + 0] = v.x; ls[c][tc4 + 1] = v.y;
        ls[c][tc4 + 2] = v.z; ls[c][tc4 + 3] = v.w;
    }
    __syncthreads();
    #pragma unroll
    for (int q = 0; q < 4; ++q) {
        int pp = tr + 16 * q;
        usx4 o;
        o[0] = f2b(ls[tc4 + 0][pp]); o[1] = f2b(ls[tc4 + 1][pp]);
        o[2] = f2b(ls[tc4 + 2][pp]); o[3] = f2b(ls[tc4 + 3][pp]);
        *(usx4*)&xt[((size_t)b * HWSZ + p0 + pp) * 256 + c0 + tc4] = o;
    }
}

// ---------------------------------------------------------------------------
// qkv_mfma: qkv[p,o] = xt[p,:] . wb[o,:]  M=65536 N=768 K=256 per batch.
// 128x128 tile, BK=32, 4 waves. mfma(B,A) so lane holds 4 consecutive o
// -> packed 8B stores.
__global__ __launch_bounds__(256) void qkv_mfma(
        const us* __restrict__ xt, const us* __restrict__ wb,
        us* __restrict__ qkv) {
    __shared__ __align__(16) us As[128 * 32];
    __shared__ __align__(16) us Bs[128 * 32];
    const int tid  = threadIdx.x;
    const int wv   = tid >> 6;
    const int lane = tid & 63;
    const int p0 = blockIdx.x * 128;
    const int o0 = blockIdx.y * 128;
    const int b  = blockIdx.z;
    const us* Ab = xt + ((size_t)b * HWSZ + p0) * 256;
    const us* Bb = wb + (size_t)o0 * 256;
    const int lr = lane & 15;
    const int k8 = lane >> 4;
    const int wm = wv >> 1, wn = wv & 1;
    const int srow = lane >> 2;
    const int sch  = (lane & 3) << 3;

    f32x4 acc[4][4];
    #pragma unroll
    for (int i = 0; i < 4; ++i)
        #pragma unroll
        for (int j = 0; j < 4; ++j) acc[i][j] = (f32x4){0.f, 0.f, 0.f, 0.f};

    for (int kt = 0; kt < 8; ++kt) {
        const int c0 = kt * 32;
        #pragma unroll
        for (int i = 0; i < 2; ++i) {
            int rb = 32 * wv + 16 * i;
            gl_lds16(Ab + (size_t)(rb + srow) * 256 + c0 + sch, &As[rb * 32]);
            gl_lds16(Bb + (size_t)(rb + srow) * 256 + c0 + sch, &Bs[rb * 32]);
        }
        __syncthreads();
        bf16x8 af[4], bg[4];
        #pragma unroll
        for (int i = 0; i < 4; ++i)
            af[i] = *(const bf16x8*)&As[(64 * wm + 16 * i + lr) * 32 + k8 * 8];
        #pragma unroll
        for (int j = 0; j < 4; ++j)
            bg[j] = *(const bf16x8*)&Bs[(64 * wn + 16 * j + lr) * 32 + k8 * 8];
        #pragma unroll
        for (int i = 0; i < 4; ++i)
            #pragma unroll
            for (int j = 0; j < 4; ++j)
                acc[i][j] = __builtin_amdgcn_mfma_f32_16x16x32_bf16(
                    bg[j], af[i], acc[i][j], 0, 0, 0);   // swapped: D[o][p]
        __syncthreads();
    }
    // swapped C/D: p = lane&15 (col), o = 4*(lane>>4)+rr (row) -> 4 consec o
    #pragma unroll
    for (int i = 0; i < 4; ++i) {
        int pr = p0 + 64 * wm + 16 * i + lr;
        #pragma unroll
        for (int j = 0; j < 4; ++j) {
            int oc = o0 + 64 * wn + 16 * j + 4 * k8;
            usx4 t;
            #pragma unroll
            for (int rr = 0; rr < 4; ++rr) t[rr] = f2b(acc[i][j][rr]);
            *(usx4*)&qkv[((size_t)b * HWSZ + pr) * 768 + oc] = t;
        }
    }
}

// ---------------------------------------------------------------------------
// attn v3: one 256-thread block per (batch,window); 16 heads in 2 passes of 8.
// K/V staged in LDS via global_load_lds; all per-lane arrays statically
// indexed (FULL unroll) to avoid scratch.
__global__ __launch_bounds__(256) void attn_kernel(
        const us* __restrict__ qkv, const us* __restrict__ xt,
        const float* __restrict__ bias_table, us* __restrict__ att) {
    const int w  = blockIdx.x & 1023;
    const int b  = blockIdx.x >> 10;
    const int wy = w >> 5, wx = w & 31;
    const int tid  = threadIdx.x;
    const int wave = tid >> 6;
    const int lane = tid & 63;

    __shared__ __align__(16) us kv8[64][256];   // 32 KB: [tok][k(8h) | v(8h)]
    __shared__ float bias_s[16][225];           // 14.4 KB

    // lane's query token
    const int p_lane = (wy * 8 + (lane >> 3)) * 256 + wx * 8 + (lane & 7);
    const size_t rowb = (size_t)b * HWSZ + p_lane;
    const int iy = lane >> 3, ix = lane & 7;

    // staging decomposition: 1 inst = 2 tokens x (k|v) x 128 us slice
    const int tt  = lane >> 5;          // token parity
    const int seg = (lane >> 4) & 1;    // 0=k, 1=v
    const int co  = (lane & 15) << 3;   // us offset in 128-us slice

    for (int n = tid; n < 3600; n += 256)
        bias_s[n & 15][n >> 4] = bias_table[n];   // flat = rel*16 + h

    #pragma unroll 1
    for (int hb = 0; hb < 2; ++hb) {
        #pragma unroll
        for (int i = 0; i < 8; ++i) {
            int t0 = wave * 16 + 2 * i;
            int t  = t0 + tt;
            int pt = (wy * 8 + (t >> 3)) * 256 + wx * 8 + (t & 7);
            const us* src = qkv + ((size_t)b * HWSZ + pt) * 768
                            + 256 + seg * 256 + hb * 128 + co;
            gl_lds16(src, &kv8[t0][0]);
        }
        __syncthreads();   // drains vmcnt + orders LDS

        #pragma unroll 1
        for (int hh = 0; hh < 2; ++hh) {
            const int h  = hb * 8 + wave * 2 + hh;
            const int hc = (wave * 2 + hh) << 4;
            const size_t gq = rowb * 768 + h * 16;
            usx8 q0 = *(const usx8*)&qkv[gq];
            usx8 q1 = *(const usx8*)&qkv[gq + 8];
            float qr[16];
            #pragma unroll
            for (int d = 0; d < 8; ++d) {
                qr[d] = b2f(q0[d]); qr[d + 8] = b2f(q1[d]);
            }
            float dots[64];
            #pragma unroll
            for (int j = 0; j < 64; ++j) {
                usx8 k0 = *(const usx8*)&kv8[j][hc];       // broadcast read
                usx8 k1 = *(const usx8*)&kv8[j][hc + 8];
                float s = 0.f;
                #pragma unroll
                for (int d = 0; d < 8; ++d) s = fmaf(qr[d], b2f(k0[d]), s);
                #pragma unroll
                for (int d = 0; d < 8; ++d) s = fmaf(qr[d + 8], b2f(k1[d]), s);
                dots[j] = s;
            }
            float mx = -1e30f;
            #pragma unroll
            for (int j = 0; j < 64; ++j) {
                dots[j] += bias_s[h][(iy - (j >> 3) + 7) * 15 + (ix - (j & 7) + 7)];
                mx = fmaxf(mx, dots[j]);
            }
            float ssum = 0.f;
            #pragma unroll
            for (int j = 0; j < 64; ++j) {
                float e = __expf(dots[j] - mx);
                dots[j] = e; ssum += e;
            }
            const float sinv = 1.0f / ssum;
            float o[16];
            #pragma unroll
            for (int d = 0; d < 16; ++d) o[d] = 0.f;
            #pragma unroll
            for (int j = 0; j < 64; ++j) {
                usx8 v0 = *(const usx8*)&kv8[j][128 + hc];
                usx8 v1 = *(const usx8*)&kv8[j][128 + hc + 8];
                float a = dots[j];
                #pragma unroll
                for (int d = 0; d < 8; ++d) o[d]     = fmaf(a, b2f(v0[d]), o[d]);
                #pragma unroll
                for (int d = 0; d < 8; ++d) o[d + 8] = fmaf(a, b2f(v1[d]), o[d + 8]);
            }
            usx8 r0 = *(const usx8*)&xt[rowb * 256 + h * 16];
            usx8 r1 = *(const usx8*)&xt[rowb * 256 + h * 16 + 8];
            usx8 s0, s1;
            #pragma unroll
            for (int d = 0; d < 8; ++d) {
                s0[d] = f2b(o[d] * sinv + b2f(r0[d]));
                s1[d] = f2b(o[d + 8] * sinv + b2f(r1[d]));
            }
            *(usx8*)&att[rowb * 256 + h * 16]     = s0;
            *(usx8*)&att[rowb * 256 + h * 16 + 8] = s1;
        }
        if (hb == 0) __syncthreads();   // everyone done before restaging
    }
}

// ---------------------------------------------------------------------------
// dwbn: NHWC depthwise 3x3 (zero-pad conv over reflect(+1) field) + BN.
// 8 channels/thread -> 16B loads/stores.
__global__ __launch_bounds__(256) void dwbn(
        const us* __restrict__ att, const float* __restrict__ dw_w,
        const float* __restrict__ ivad, us* __restrict__ ybn) {
    const int tid = threadIdx.x;
    const int c8 = (tid & 31) * 8;
    const int pl = tid >> 5;           // 0..7
    const int b  = blockIdx.y;
    const int pbase = blockIdx.x * 256;
    float w[9][8], iv[8], ad[8];
    #pragma unroll
    for (int cc = 0; cc < 8; ++cc) {
        #pragma unroll
        for (int k = 0; k < 9; ++k) w[k][cc] = dw_w[(c8 + cc) * 9 + k];
        iv[cc] = ivad[c8 + cc];
        ad[cc] = ivad[256 + c8 + cc];
    }
    const us* ab = att + (size_t)b * HWSZ * 256;
    us* yb = ybn + (size_t)b * HWSZ * 256;
    for (int it = 0; it < 32; ++it) {
        const int p = pbase + it * 8 + pl;
        const int y = p >> 8, x = p & 255;
        float acc[8] = {0.f, 0.f, 0.f, 0.f, 0.f, 0.f, 0.f, 0.f};
        #pragma unroll
        for (int dy = -1; dy <= 1; ++dy) {
            int yy = y + dy;
            if (yy < 0) continue;        // zero pad (conv)
            if (yy > 255) yy = 254;      // reflect pad (pad_out)
            #pragma unroll
            for (int dx = -1; dx <= 1; ++dx) {
                int xx = x + dx;
                if (xx < 0) continue;
                if (xx > 255) xx = 254;
                usx8 vv = *(const usx8*)&ab[((size_t)(yy << 8) + xx) * 256 + c8];
                const int k = (dy + 1) * 3 + dx + 1;
                #pragma unroll
                for (int cc = 0; cc < 8; ++cc)
                    acc[cc] = fmaf(w[k][cc], b2f(vv[cc]), acc[cc]);
            }
        }
        usx8 o;
        #pragma unroll
        for (int cc = 0; cc < 8; ++cc) o[cc] = f2b(acc[cc] * iv[cc] + ad[cc]);
        *(usx8*)&yb[(size_t)p * 256 + c8] = o;
    }
}

// ---------------------------------------------------------------------------
// pw_mfma: out[o,p] (NCHW f32) = ybn[p,:] . pwb[o,:]   M=65536 N=256 K=256
__global__ __launch_bounds__(256) void pw_mfma(
        const us* __restrict__ ybn, const us* __restrict__ pwb,
        float* __restrict__ out) {
    __shared__ __align__(16) us As[128 * 32];
    __shared__ __align__(16) us Bs[128 * 32];
    const int tid  = threadIdx.x;
    const int wv   = tid >> 6;
    const int lane = tid & 63;
    const int p0 = blockIdx.x * 128;
    const int o0 = blockIdx.y * 128;
    const int b  = blockIdx.z;
    const us* Ab = ybn + ((size_t)b * HWSZ + p0) * 256;
    const us* Bb = pwb + (size_t)o0 * 256;
    const int lr = lane & 15;
    const int k8 = lane >> 4;
    const int wm = wv >> 1, wn = wv & 1;
    const int srow = lane >> 2;
    const int sch  = (lane & 3) << 3;

    f32x4 acc[4][4];
    #pragma unroll
    for (int i = 0; i < 4; ++i)
        #pragma unroll
        for (int j = 0; j < 4; ++j) acc[i][j] = (f32x4){0.f, 0.f, 0.f, 0.f};

    for (int kt = 0; kt < 8; ++kt) {
        const int c0 = kt * 32;
        #pragma unroll
        for (int i = 0; i < 2; ++i) {
            int rb = 32 * wv + 16 * i;
            gl_lds16(Ab + (size_t)(rb + srow) * 256 + c0 + sch, &As[rb * 32]);
            gl_lds16(Bb + (size_t)(rb + srow) * 256 + c0 + sch, &Bs[rb * 32]);
        }
        __syncthreads();
        bf16x8 af[4], bg[4];
        #pragma unroll
        for (int i = 0; i < 4; ++i)
            af[i] = *(const bf16x8*)&As[(64 * wm + 16 * i + lr) * 32 + k8 * 8];
        #pragma unroll
        for (int j = 0; j < 4; ++j)
            bg[j] = *(const bf16x8*)&Bs[(64 * wn + 16 * j + lr) * 32 + k8 * 8];
        #pragma unroll
        for (int i = 0; i < 4; ++i)
            #pragma unroll
            for (int j = 0; j < 4; ++j)
                acc[i][j] = __builtin_amdgcn_mfma_f32_16x16x32_bf16(
                    af[i], bg[j], acc[i][j], 0, 0, 0);
        __syncthreads();
    }
    // row=p (4 consecutive per lane) -> float4 store into NCHW out[o][p]
    #pragma unroll
    for (int i = 0; i < 4; ++i) {
        int pr = p0 + 64 * wm + 16 * i + 4 * k8;
        #pragma unroll
        for (int j = 0; j < 4; ++j) {
            int oc = o0 + 64 * wn + 16 * j + lr;
            *(f32x4*)&out[((size_t)b * 256 + oc) * HWSZ + pr] = acc[i][j];
        }
    }
}

// ---------------------------------------------------------------------------
extern "C" void kernel_launch(void* const* d_in, const int* in_sizes, int n_in,
                              void* d_out, int out_size, void* d_ws, size_t ws_size,
                              hipStream_t stream) {
    const float* x          = (const float*)d_in[0];
    const float* qkv_w      = (const float*)d_in[1];
    const float* bias_table = (const float*)d_in[2];
    const float* dw_w       = (const float*)d_in[3];
    const float* bn_gamma   = (const float*)d_in[4];
    const float* bn_beta    = (const float*)d_in[5];
    const float* bn_mean    = (const float*)d_in[6];
    const float* bn_var     = (const float*)d_in[7];
    const float* pw_w       = (const float*)d_in[8];
    float* out = (float*)d_out;

    // workspace layout (ybn aliases xt: xt is dead after attn)
    char* ws = (char*)d_ws;
    us*    xt   = (us*)ws;                          //  67,108,864 B
    us*    qkv  = (us*)(ws + 67108864);             // 201,326,592 B
    us*    att  = (us*)(ws + 268435456);            //  67,108,864 B
    us*    wb   = (us*)(ws + 335544320);            //     393,216 B
    us*    pwb  = (us*)(ws + 335937536);            //     131,072 B
    float* ivad = (float*)(ws + 336068608);         //       2,048 B
    us*    ybn  = xt;                               // alias

    prep<<<768, 256, 0, stream>>>(qkv_w, pw_w, bn_gamma, bn_beta, bn_mean,
                                  bn_var, wb, pwb, ivad);
    transpose_x<<<dim3(1024, 4, 2), 256, 0, stream>>>(x, xt);
    qkv_mfma<<<dim3(512, 6, 2), 256, 0, stream>>>(xt, wb, qkv);
    attn_kernel<<<2048, 256, 0, stream>>>(qkv, xt, bias_table, att);
    dwbn<<<dim3(256, 2), 256, 0, stream>>>(att, dw_w, ivad, ybn);
    pw_mfma<<<dim3(512, 2, 2), 256, 0, stream>>>(ybn, pwb, out);
}